// Round 2
// baseline (1130.732 us; speedup 1.0000x reference)
//
#include <hip/hip_runtime.h>
#include <math.h>

#define B 16
#define N 20000
#define H 640
#define A 128
#define LN_EPS 1e-5f
#define SCALE 0.08838834764831843f  // 128^-0.5

// ---------------------------------------------------------------------------
// Kernel 1: qk[b][h] = SCALE * sum_a Wk[a][h] * (sum_h' Wq[a][h'] * pos[b][h'])
// Wave-per-row coalesced dots for the Wq matvec.
// ---------------------------------------------------------------------------
__global__ __launch_bounds__(256) void qk_kernel(
    const float* __restrict__ pos, const float* __restrict__ Wq,
    const float* __restrict__ Wk, float* __restrict__ qk) {
  int b = blockIdx.x;
  int tid = threadIdx.x;
  int wid = tid >> 6, lane = tid & 63;
  __shared__ float sp[H];
  __shared__ float sq[A];
  for (int i = tid; i < H; i += 256) sp[i] = pos[b * H + i];
  __syncthreads();

  // q[a] = Wq[a,:].pos  -- wave w handles rows a in [32w, 32w+32)
  float2 spf[5];
  const float2* sp2 = (const float2*)sp;
#pragma unroll
  for (int k = 0; k < 5; k++) spf[k] = sp2[lane + 64 * k];
  for (int j = 0; j < 32; j++) {
    int a = wid * 32 + j;
    const float2* wr = (const float2*)(Wq + (size_t)a * H);
    float dot = 0.f;
#pragma unroll
    for (int k = 0; k < 5; k++) {
      float2 v = wr[lane + 64 * k];
      dot += v.x * spf[k].x + v.y * spf[k].y;
    }
#pragma unroll
    for (int off = 32; off >= 1; off >>= 1) dot += __shfl_xor(dot, off);
    if (lane == 0) sq[a] = dot;
  }
  __syncthreads();

  // qk[h] = SCALE * sum_a Wk[a][h] * sq[a]   (coalesced across threads)
  for (int h = tid; h < H; h += 256) {
    float acc = 0.f;
    for (int a = 0; a < A; a++) acc += Wk[(size_t)a * H + h] * sq[a];
    qk[b * H + h] = acc * SCALE;
  }
}

// ---------------------------------------------------------------------------
// Kernel 2: single-pass online-softmax weighted accumulation of gene_hiddens.
// Half-wave per row: lanes 0-31 own row 2p, lanes 32-63 own row 2p+1.
// Each lane loads 5 float4 (16 B/lane, fully coalesced: two 512-B extents on
// adjacent rows). 32-wide shuffle reduce (5 hops) + 2 broadcasts per pair.
// Wave-uniform fast path skips the accumulator rescale unless a new running
// max appears (~ln(#rows) times per wave).
// ---------------------------------------------------------------------------
__global__ __launch_bounds__(256) void pass1_kernel(
    const float* __restrict__ gh, const float* __restrict__ qk,
    float* __restrict__ pm, float* __restrict__ pl, float* __restrict__ po,
    int blocks_per_b) {
  int b = blockIdx.x / blocks_per_b;
  int blk = blockIdx.x - b * blocks_per_b;
  int wid = threadIdx.x >> 6;
  int lane = threadIdx.x & 63;
  int half = lane >> 5;
  int li = lane & 31;
  int w = blk * 4 + wid;          // wave index within batch
  int nw = blocks_per_b * 4;      // waves per batch
  int npairs = N / 2;

  const float4* qk4 = (const float4*)(qk + b * H);
  float4 qv[5];
#pragma unroll
  for (int k = 0; k < 5; k++) qv[k] = qk4[li + 32 * k];

  const float* ghb = gh + (size_t)b * N * H;
  float m = -INFINITY, l = 0.f;
  float4 o[5];
#pragma unroll
  for (int k = 0; k < 5; k++) o[k] = make_float4(0.f, 0.f, 0.f, 0.f);

  for (int p = w; p < npairs; p += nw) {
    const float4* row = (const float4*)(ghb + (size_t)(2 * p + half) * H);
    float4 hv[5];
#pragma unroll
    for (int k = 0; k < 5; k++) hv[k] = row[li + 32 * k];
    float dot = 0.f;
#pragma unroll
    for (int k = 0; k < 5; k++) {
      dot += hv[k].x * qv[k].x + hv[k].y * qv[k].y +
             hv[k].z * qv[k].z + hv[k].w * qv[k].w;
    }
#pragma unroll
    for (int off = 16; off >= 1; off >>= 1) dot += __shfl_xor(dot, off);
    float sA = __shfl(dot, 0);   // score of row 2p   (uniform on wave)
    float sB = __shfl(dot, 32);  // score of row 2p+1 (uniform on wave)
    float smax = fmaxf(sA, sB);
    if (smax <= m) {             // wave-uniform fast path: no rescale
      float wtA = __expf(sA - m), wtB = __expf(sB - m);
      l += wtA + wtB;
      float wt = half ? wtB : wtA;
#pragma unroll
      for (int k = 0; k < 5; k++) {
        o[k].x += wt * hv[k].x; o[k].y += wt * hv[k].y;
        o[k].z += wt * hv[k].z; o[k].w += wt * hv[k].w;
      }
    } else {                     // new max: rescale (rare)
      float alpha = __expf(m - smax);  // exp(-inf)=0 on first iteration
      float wtA = __expf(sA - smax), wtB = __expf(sB - smax);
      l = l * alpha + wtA + wtB;
      float wt = half ? wtB : wtA;
#pragma unroll
      for (int k = 0; k < 5; k++) {
        o[k].x = o[k].x * alpha + wt * hv[k].x;
        o[k].y = o[k].y * alpha + wt * hv[k].y;
        o[k].z = o[k].z * alpha + wt * hv[k].z;
        o[k].w = o[k].w * alpha + wt * hv[k].w;
      }
      m = smax;
    }
  }

  // fold upper half into lower (both halves end with identical full sums)
#pragma unroll
  for (int k = 0; k < 5; k++) {
    o[k].x += __shfl_xor(o[k].x, 32);
    o[k].y += __shfl_xor(o[k].y, 32);
    o[k].z += __shfl_xor(o[k].z, 32);
    o[k].w += __shfl_xor(o[k].w, 32);
  }

  // combine the 4 wave states within the block
  __shared__ float wm[4], wl[4];
  __shared__ float4 wo4[4][H / 4];
  if (lane == 0) { wm[wid] = m; wl[wid] = l; }
  if (half == 0) {
#pragma unroll
    for (int k = 0; k < 5; k++) wo4[wid][li + 32 * k] = o[k];
  }
  __syncthreads();
  float M = fmaxf(fmaxf(wm[0], wm[1]), fmaxf(wm[2], wm[3]));
  float e0 = __expf(wm[0] - M), e1 = __expf(wm[1] - M);
  float e2 = __expf(wm[2] - M), e3 = __expf(wm[3] - M);
  const float* wof = (const float*)wo4;
  int idx = b * blocks_per_b + blk;
  for (int e = threadIdx.x; e < H; e += 256) {
    po[(size_t)idx * H + e] = wof[e] * e0 + wof[H + e] * e1 +
                              wof[2 * H + e] * e2 + wof[3 * H + e] * e3;
  }
  if (threadIdx.x == 0) {
    pm[idx] = M;
    pl[idx] = wl[0] * e0 + wl[1] * e1 + wl[2] * e2 + wl[3] * e3;
  }
}

// ---------------------------------------------------------------------------
// Kernel 3: combine partials -> s[640]; pooled = Wv @ s (wave-per-row,
// coalesced); LayerNorm -> out. One block per batch, 640 threads (10 waves).
// ---------------------------------------------------------------------------
__device__ __forceinline__ float block_reduce_640(float v, float* red) {
  int lane = threadIdx.x & 63, wid = threadIdx.x >> 6;
#pragma unroll
  for (int off = 32; off >= 1; off >>= 1) v += __shfl_xor(v, off);
  __syncthreads();
  if (lane == 0) red[wid] = v;
  __syncthreads();
  float t = 0.f;
#pragma unroll
  for (int j = 0; j < 10; j++) t += red[j];
  return t;
}

__global__ __launch_bounds__(640) void finalize_kernel(
    const float* __restrict__ pm, const float* __restrict__ pl,
    const float* __restrict__ po, const float* __restrict__ Wv,
    const float* __restrict__ gamma, const float* __restrict__ beta,
    float* __restrict__ out, int blocks_per_b) {
  int b = blockIdx.x;
  int tid = threadIdx.x;  // 0..639
  int wid = tid >> 6, lane = tid & 63;
  __shared__ float sh[H];
  __shared__ float pooled[H];
  __shared__ float red[16];

  float M = -INFINITY;
  for (int j = 0; j < blocks_per_b; j++) M = fmaxf(M, pm[b * blocks_per_b + j]);
  float L = 0.f;
  for (int j = 0; j < blocks_per_b; j++)
    L += pl[b * blocks_per_b + j] * __expf(pm[b * blocks_per_b + j] - M);
  float invL = 1.f / L;

  float s = 0.f;
  for (int j = 0; j < blocks_per_b; j++) {
    s += po[(size_t)(b * blocks_per_b + j) * H + tid] *
         __expf(pm[b * blocks_per_b + j] - M);
  }
  sh[tid] = s * invL;
  __syncthreads();

  // pooled[r] = Wv[r,:] . sh  -- wave y handles rows [64y, 64y+64), coalesced
  float2 shf[5];
  const float2* sh2 = (const float2*)sh;
#pragma unroll
  for (int k = 0; k < 5; k++) shf[k] = sh2[lane + 64 * k];
  for (int j = 0; j < 64; j++) {
    int r = wid * 64 + j;
    const float2* wr = (const float2*)(Wv + (size_t)r * H);
    float dot = 0.f;
#pragma unroll
    for (int k = 0; k < 5; k++) {
      float2 v = wr[lane + 64 * k];
      dot += v.x * shf[k].x + v.y * shf[k].y;
    }
#pragma unroll
    for (int off = 32; off >= 1; off >>= 1) dot += __shfl_xor(dot, off);
    if (lane == 0) pooled[r] = dot;
  }
  __syncthreads();

  float acc = pooled[tid];
  float mu = block_reduce_640(acc, red) * (1.f / H);
  float d = acc - mu;
  float var = block_reduce_640(d * d, red) * (1.f / H);
  out[b * H + tid] = d * rsqrtf(var + LN_EPS) * gamma[tid] + beta[tid];
}

// ---------------------------------------------------------------------------
extern "C" void kernel_launch(void* const* d_in, const int* in_sizes, int n_in,
                              void* d_out, int out_size, void* d_ws, size_t ws_size,
                              hipStream_t stream) {
  const float* gh    = (const float*)d_in[0];  // [16,20000,640]
  const float* pos   = (const float*)d_in[1];  // [16,640]
  const float* Wq    = (const float*)d_in[2];  // [128,640]
  const float* Wk    = (const float*)d_in[3];  // [128,640]
  const float* Wv    = (const float*)d_in[4];  // [640,640]
  const float* gamma = (const float*)d_in[5];  // [640]
  const float* beta  = (const float*)d_in[6];  // [640]
  float* out = (float*)d_out;
  float* ws = (float*)d_ws;

  int blocks_per_b = 64;  // 64 blocks x 4 waves = 256 waves/batch
  while (blocks_per_b > 1 &&
         (size_t)(B * H + 2 * B * 64 + B * blocks_per_b * H) * 4 > ws_size)
    blocks_per_b >>= 1;

  float* qk = ws;                         // B*H      = 10240 floats
  float* pm = ws + B * H;                 // B*64 max
  float* pl = pm + B * 64;                // B*64 max
  float* po = pl + B * 64;                // B*blocks_per_b*H floats

  qk_kernel<<<B, 256, 0, stream>>>(pos, Wq, Wk, qk);
  pass1_kernel<<<B * blocks_per_b, 256, 0, stream>>>(gh, qk, pm, pl, po,
                                                     blocks_per_b);
  finalize_kernel<<<B, 640, 0, stream>>>(pm, pl, po, Wv, gamma, beta, out,
                                         blocks_per_b);
}